// Round 1
// baseline (238.259 us; speedup 1.0000x reference)
//
#include <hip/hip_runtime.h>
#include <hip/hip_bf16.h>

#define B_ 8
#define T_ 2048
#define E_ 64
#define H_ 8
#define DK_ 8
#define FF_ 256
#define NROWS (B_*T_)

typedef __attribute__((ext_vector_type(4))) float f32x4;
typedef __attribute__((ext_vector_type(8))) short short8;

__device__ __forceinline__ unsigned short f2bf(float f) {
    __hip_bfloat16 h = __float2bfloat16(f);
    return *reinterpret_cast<unsigned short*>(&h);
}
__device__ __forceinline__ float bflo(unsigned int u) { return __uint_as_float(u << 16); }
__device__ __forceinline__ float bfhi(unsigned int u) { return __uint_as_float(u & 0xffff0000u); }

__device__ __forceinline__ float fast_exp2(float x) {
#if __has_builtin(__builtin_amdgcn_exp2f)
    return __builtin_amdgcn_exp2f(x);
#else
    return exp2f(x);
#endif
}

// ---------------------------------------------------------------------------
// Kernel 1: QKV projection + cos(.+theta) + bf16 pack to [B,H,T,DK] layout.
// q additionally scaled by log2(e)/sqrt(DK) so attention can use raw exp2.
// ---------------------------------------------------------------------------
__global__ __launch_bounds__(256) void qkv_kernel(
    const float* __restrict__ x,
    const float* __restrict__ Wq, const float* __restrict__ bq,
    const float* __restrict__ Wk, const float* __restrict__ bk,
    const float* __restrict__ Wv, const float* __restrict__ bv,
    const float* __restrict__ theta_attn,
    unsigned short* __restrict__ qb, unsigned short* __restrict__ kb,
    unsigned short* __restrict__ vbuf)
{
    __shared__ unsigned short xs[64][68];   // x^T bf16: xs[k][row]
    __shared__ float ws[64][196];           // W^T fp32: ws[k][c], c in [0,192)
    const int tid = threadIdx.x;
    const int n0 = blockIdx.x * 64;

    {
        const float4* xg = (const float4*)(x + (size_t)n0 * 64);
        #pragma unroll
        for (int t = 0; t < 4; t++) {
            int fi = tid + t * 256;          // 1024 float4 = 64x64 floats
            float4 v = xg[fi];
            int r = fi >> 4;
            int k0 = (fi & 15) * 4;
            xs[k0+0][r] = f2bf(v.x);
            xs[k0+1][r] = f2bf(v.y);
            xs[k0+2][r] = f2bf(v.z);
            xs[k0+3][r] = f2bf(v.w);
        }
        const float* Wm[3] = {Wq, Wk, Wv};
        #pragma unroll
        for (int m = 0; m < 3; m++) {
            const float4* wg = (const float4*)Wm[m];
            #pragma unroll
            for (int t = 0; t < 4; t++) {
                int fi = tid + t * 256;
                float4 v = wg[fi];
                int j = fi >> 4;
                int k0 = (fi & 15) * 4;
                ws[k0+0][m*64+j] = v.x;
                ws[k0+1][m*64+j] = v.y;
                ws[k0+2][m*64+j] = v.z;
                ws[k0+3][m*64+j] = v.w;
            }
        }
    }
    __syncthreads();

    const int rg = tid & 15, cg = tid >> 4;
    const int r0 = rg * 4, c0 = cg * 12;
    float acc[4][12] = {};

    #pragma unroll 8
    for (int k = 0; k < 64; k++) {
        uint2 au = *(const uint2*)&xs[k][r0];
        float a_[4] = { bflo(au.x), bfhi(au.x), bflo(au.y), bfhi(au.y) };
        float4 b0 = *(const float4*)&ws[k][c0];
        float4 b1 = *(const float4*)&ws[k][c0+4];
        float4 b2 = *(const float4*)&ws[k][c0+8];
        float b_[12] = {b0.x,b0.y,b0.z,b0.w, b1.x,b1.y,b1.z,b1.w, b2.x,b2.y,b2.z,b2.w};
        #pragma unroll
        for (int i = 0; i < 4; i++)
            #pragma unroll
            for (int j = 0; j < 12; j++)
                acc[i][j] += a_[i] * b_[j];
    }

    const float th = *theta_attn;
    const float QS = 0.51006980f;   // log2(e)/sqrt(8)
    const float* bias[3] = {bq, bk, bv};
    unsigned short* outp[3] = {qb, kb, vbuf};
    #pragma unroll
    for (int i = 0; i < 4; i++) {
        int n = n0 + r0 + i;
        int bI = n >> 11, tI = n & 2047;
        #pragma unroll
        for (int j = 0; j < 12; j++) {
            int c = c0 + j;
            int m = c >> 6, cc = c & 63;
            int hI = cc >> 3, dI = cc & 7;
            float val = __cosf(acc[i][j] + bias[m][cc] + th);
            if (m == 0) val *= QS;
            size_t idx = ((size_t)(bI*8 + hI) * 2048 + tI) * 8 + dI;
            outp[m][idx] = f2bf(val);
        }
    }
}

// ---------------------------------------------------------------------------
// Kernel 2: flash attention (no-max softmax; scores bounded by 8/sqrt(8)).
// 16x16x32 bf16 MFMA; DK=8 zero-padded. One 16-row q-tile per wave.
// ---------------------------------------------------------------------------
__global__ __launch_bounds__(256) void attn_kernel(
    const unsigned short* __restrict__ qb,
    const unsigned short* __restrict__ kb,
    const unsigned short* __restrict__ vb,
    float* __restrict__ attn)
{
    __shared__ unsigned short Ks[1024*8];     // K rows (bf16), half of T
    __shared__ unsigned short Vt[8*1032];     // V^T (padded stride 1032)
    __shared__ unsigned short Ps[4*640];      // per-wave P scratch [16][40]

    const int tid = threadIdx.x;
    const int head = blockIdx.x >> 5;         // b*8 + h
    const int qblk = blockIdx.x & 31;
    const size_t hoff = (size_t)head * T_ * DK_;

    const int wave = tid >> 6, lane = tid & 63;
    const int col = lane & 15, quad = lane >> 4;
    const int q0 = qblk * 64 + wave * 16;

    short8 aq = {0,0,0,0,0,0,0,0};
    if (lane < 16)
        aq = *(const short8*)(qb + hoff + (size_t)(q0 + lane) * 8);

    f32x4 oacc = {0.f, 0.f, 0.f, 0.f};
    const f32x4 zero4 = {0.f, 0.f, 0.f, 0.f};
    float lsum[4] = {0.f, 0.f, 0.f, 0.f};

    unsigned short* pw = &Ps[wave*640 + (quad*4)*40 + col];
    const short8* pr = (const short8*)&Ps[wave*640 + col*40 + quad*8];

    for (int half = 0; half < 2; half++) {
        __syncthreads();   // prior compute done before LDS overwrite
        {
            const uint4* kg = (const uint4*)(kb + hoff + (size_t)half*1024*8);
            const uint4* vg = (const uint4*)(vb + hoff + (size_t)half*1024*8);
            uint4* kl = (uint4*)Ks;
            #pragma unroll
            for (int it = 0; it < 4; it++) {
                int s = tid + it * 256;
                kl[s] = kg[s];
                union { uint4 u; unsigned short us[8]; } cv;
                cv.u = vg[s];
                #pragma unroll
                for (int d = 0; d < 8; d++)
                    Vt[d*1032 + s] = cv.us[d];
            }
        }
        __syncthreads();

        for (int s0 = 0; s0 < 1024; s0 += 32) {
            short8 kb0 = {0,0,0,0,0,0,0,0}, kb1 = {0,0,0,0,0,0,0,0};
            if (lane < 16) {
                kb0 = *(const short8*)&Ks[(s0 + lane) * 8];
                kb1 = *(const short8*)&Ks[(s0 + 16 + lane) * 8];
            }
            f32x4 S0 = __builtin_amdgcn_mfma_f32_16x16x32_bf16(aq, kb0, zero4, 0, 0, 0);
            f32x4 S1 = __builtin_amdgcn_mfma_f32_16x16x32_bf16(aq, kb1, zero4, 0, 0, 0);
            #pragma unroll
            for (int r = 0; r < 4; r++) {
                float p0 = fast_exp2(S0[r]);
                float p1 = fast_exp2(S1[r]);
                unsigned int u0 = __float_as_uint(p0);
                unsigned int u1 = __float_as_uint(p1);
                // accumulate the *bf16-truncated* p so numerator/denominator match
                lsum[r] += bfhi(u0) + bfhi(u1);
                pw[r*40]      = (unsigned short)(u0 >> 16);
                pw[r*40 + 16] = (unsigned short)(u1 >> 16);
            }
            __asm__ volatile("s_waitcnt lgkmcnt(0)" ::: "memory");
            short8 pa = *pr;
            short8 vb8 = {0,0,0,0,0,0,0,0};
            if (col < 8)
                vb8 = *(const short8*)&Vt[col*1032 + s0 + quad*8];
            oacc = __builtin_amdgcn_mfma_f32_16x16x32_bf16(pa, vb8, oacc, 0, 0, 0);
        }
    }

    #pragma unroll
    for (int m = 1; m <= 8; m <<= 1) {
        #pragma unroll
        for (int r = 0; r < 4; r++)
            lsum[r] += __shfl_xor(lsum[r], m, 16);
    }

    if (col < 8) {
        const int bI = head >> 3, hI = head & 7;
        #pragma unroll
        for (int r = 0; r < 4; r++) {
            int trow = q0 + quad * 4 + r;
            attn[((size_t)bI * 2048 + trow) * 64 + hI * 8 + col] = oacc[r] / lsum[r];
        }
    }
}

// ---------------------------------------------------------------------------
// Kernel 3: y = attn@Wo^T + bo; x1 = LN(x+y); qout = cos(x1)*cos(theta_ffn)
// ---------------------------------------------------------------------------
__global__ __launch_bounds__(256) void postattn_kernel(
    const float* __restrict__ attn, const float* __restrict__ x,
    const float* __restrict__ Wo, const float* __restrict__ bo,
    const float* __restrict__ g1, const float* __restrict__ be1,
    const float* __restrict__ theta_ffn,
    float* __restrict__ x1, float* __restrict__ qout)
{
    __shared__ float At[64][68];
    __shared__ float Wt[64][68];
    __shared__ float Y[64][65];
    const int tid = threadIdx.x;
    const int n0 = blockIdx.x * 64;

    {
        const float4* ag = (const float4*)(attn + (size_t)n0 * 64);
        const float4* wg = (const float4*)Wo;
        #pragma unroll
        for (int t = 0; t < 4; t++) {
            int fi = tid + t * 256;
            int r = fi >> 4, k0 = (fi & 15) * 4;
            float4 v = ag[fi];
            At[k0+0][r]=v.x; At[k0+1][r]=v.y; At[k0+2][r]=v.z; At[k0+3][r]=v.w;
            float4 w = wg[fi];
            Wt[k0+0][r]=w.x; Wt[k0+1][r]=w.y; Wt[k0+2][r]=w.z; Wt[k0+3][r]=w.w;
        }
    }
    __syncthreads();

    const int rg = tid & 15, cg = tid >> 4;
    const int r0 = rg * 4, c0 = cg * 4;
    float acc[4][4] = {};
    #pragma unroll 8
    for (int k = 0; k < 64; k++) {
        float4 a = *(const float4*)&At[k][r0];
        float4 b = *(const float4*)&Wt[k][c0];
        float a_[4] = {a.x,a.y,a.z,a.w};
        float b_[4] = {b.x,b.y,b.z,b.w};
        #pragma unroll
        for (int i = 0; i < 4; i++)
            #pragma unroll
            for (int j = 0; j < 4; j++)
                acc[i][j] += a_[i] * b_[j];
    }
    float4 bv = *(const float4*)&bo[c0];
    float bb[4] = {bv.x, bv.y, bv.z, bv.w};
    #pragma unroll
    for (int i = 0; i < 4; i++)
        #pragma unroll
        for (int j = 0; j < 4; j++)
            Y[r0+i][c0+j] = acc[i][j] + bb[j];
    __syncthreads();

    const int row = tid >> 2, sg = (tid & 3) * 16;
    const int n = n0 + row;
    float vals[16], s1 = 0.f, s2 = 0.f;
    const float* xr = x + (size_t)n * 64 + sg;
    #pragma unroll
    for (int e = 0; e < 16; e++) {
        float vv = Y[row][sg + e] + xr[e];
        vals[e] = vv; s1 += vv; s2 += vv * vv;
    }
    s1 += __shfl_xor(s1, 1, 4); s1 += __shfl_xor(s1, 2, 4);
    s2 += __shfl_xor(s2, 1, 4); s2 += __shfl_xor(s2, 2, 4);
    float mean = s1 * 0.015625f;
    float var = s2 * 0.015625f - mean * mean;
    float rstd = rsqrtf(var + 1e-5f);
    float cth = __cosf(*theta_ffn);
    float* x1r = x1 + (size_t)n * 64;
    float* qr = qout + (size_t)n * 64;
    #pragma unroll
    for (int e = 0; e < 16; e++) {
        int c = sg + e;
        float xv = (vals[e] - mean) * rstd * g1[c] + be1[c];
        x1r[c] = xv;
        qr[c] = __cosf(xv) * cth;
    }
}

// ---------------------------------------------------------------------------
// Kernel 4: h = relu(qout@W1^T + b1)   -> hbuf [NROWS,256]
// ---------------------------------------------------------------------------
__global__ __launch_bounds__(256) void ffn1_kernel(
    const float* __restrict__ qout, const float* __restrict__ W1,
    const float* __restrict__ b1, float* __restrict__ hbuf)
{
    __shared__ float Qt[64][68];
    __shared__ unsigned short W1t[64][264];
    const int tid = threadIdx.x;
    const int n0 = blockIdx.x * 64;
    {
        const float4* qg = (const float4*)(qout + (size_t)n0 * 64);
        #pragma unroll
        for (int t = 0; t < 4; t++) {
            int fi = tid + t * 256;
            int r = fi >> 4, k0 = (fi & 15) * 4;
            float4 v = qg[fi];
            Qt[k0+0][r]=v.x; Qt[k0+1][r]=v.y; Qt[k0+2][r]=v.z; Qt[k0+3][r]=v.w;
        }
        const float4* wg = (const float4*)W1;
        #pragma unroll
        for (int t = 0; t < 16; t++) {
            int fi = tid + t * 256;     // 4096 float4 = 256x64
            int ff = fi >> 4, k0 = (fi & 15) * 4;
            float4 v = wg[fi];
            W1t[k0+0][ff]=f2bf(v.x); W1t[k0+1][ff]=f2bf(v.y);
            W1t[k0+2][ff]=f2bf(v.z); W1t[k0+3][ff]=f2bf(v.w);
        }
    }
    __syncthreads();

    const int rg = tid & 15, cg = tid >> 4;
    const int r0 = rg * 4, c0 = cg * 16;
    float acc[4][16] = {};
    #pragma unroll 4
    for (int k = 0; k < 64; k++) {
        float4 a = *(const float4*)&Qt[k][r0];
        float a_[4] = {a.x, a.y, a.z, a.w};
        uint4 w0 = *(const uint4*)&W1t[k][c0];
        uint4 w1 = *(const uint4*)&W1t[k][c0 + 8];
        float b_[16] = { bflo(w0.x), bfhi(w0.x), bflo(w0.y), bfhi(w0.y),
                         bflo(w0.z), bfhi(w0.z), bflo(w0.w), bfhi(w0.w),
                         bflo(w1.x), bfhi(w1.x), bflo(w1.y), bfhi(w1.y),
                         bflo(w1.z), bfhi(w1.z), bflo(w1.w), bfhi(w1.w) };
        #pragma unroll
        for (int i = 0; i < 4; i++)
            #pragma unroll
            for (int j = 0; j < 16; j++)
                acc[i][j] += a_[i] * b_[j];
    }
    #pragma unroll
    for (int i = 0; i < 4; i++) {
        int n = n0 + r0 + i;
        float o[16];
        #pragma unroll
        for (int j = 0; j < 16; j++)
            o[j] = fmaxf(acc[i][j] + b1[c0 + j], 0.f);
        float4* hg = (float4*)(hbuf + (size_t)n * 256 + c0);
        hg[0] = make_float4(o[0],o[1],o[2],o[3]);
        hg[1] = make_float4(o[4],o[5],o[6],o[7]);
        hg[2] = make_float4(o[8],o[9],o[10],o[11]);
        hg[3] = make_float4(o[12],o[13],o[14],o[15]);
    }
}

// ---------------------------------------------------------------------------
// Kernel 5: f = h@W2^T + b2; out = LN(x1 + f)  (final output, fp32)
// ---------------------------------------------------------------------------
__global__ __launch_bounds__(256) void ffn2_kernel(
    const float* __restrict__ hbuf, const float* __restrict__ x1v,
    const float* __restrict__ W2, const float* __restrict__ b2,
    const float* __restrict__ g2, const float* __restrict__ be2,
    float* __restrict__ outp)
{
    __shared__ unsigned short Ht[128][72];
    __shared__ unsigned short W2t[128][72];
    __shared__ float Y[64][65];
    const int tid = threadIdx.x;
    const int n0 = blockIdx.x * 64;
    const int rg = tid & 15, cg = tid >> 4;
    const int r0 = rg * 4, c0 = cg * 4;
    float acc[4][4] = {};

    for (int kc = 0; kc < 2; kc++) {
        __syncthreads();
        {
            #pragma unroll
            for (int t = 0; t < 8; t++) {
                int fi = tid + t * 256;       // 2048 float4 = 64x128
                int r = fi >> 5, k0 = (fi & 31) * 4;
                float4 v = *(const float4*)(hbuf + (size_t)(n0 + r) * 256 + kc * 128 + k0);
                Ht[k0+0][r]=f2bf(v.x); Ht[k0+1][r]=f2bf(v.y);
                Ht[k0+2][r]=f2bf(v.z); Ht[k0+3][r]=f2bf(v.w);
            }
            #pragma unroll
            for (int t = 0; t < 8; t++) {
                int fi = tid + t * 256;
                int e = fi >> 5, k0 = (fi & 31) * 4;
                float4 v = *(const float4*)(W2 + (size_t)e * 256 + kc * 128 + k0);
                W2t[k0+0][e]=f2bf(v.x); W2t[k0+1][e]=f2bf(v.y);
                W2t[k0+2][e]=f2bf(v.z); W2t[k0+3][e]=f2bf(v.w);
            }
        }
        __syncthreads();
        #pragma unroll 4
        for (int k = 0; k < 128; k++) {
            uint2 au = *(const uint2*)&Ht[k][r0];
            uint2 bu = *(const uint2*)&W2t[k][c0];
            float a_[4] = { bflo(au.x), bfhi(au.x), bflo(au.y), bfhi(au.y) };
            float b_[4] = { bflo(bu.x), bfhi(bu.x), bflo(bu.y), bfhi(bu.y) };
            #pragma unroll
            for (int i = 0; i < 4; i++)
                #pragma unroll
                for (int j = 0; j < 4; j++)
                    acc[i][j] += a_[i] * b_[j];
        }
    }

    float4 bv = *(const float4*)&b2[c0];
    float bb[4] = {bv.x, bv.y, bv.z, bv.w};
    #pragma unroll
    for (int i = 0; i < 4; i++)
        #pragma unroll
        for (int j = 0; j < 4; j++)
            Y[r0+i][c0+j] = acc[i][j] + bb[j];
    __syncthreads();

    const int row = tid >> 2, sg = (tid & 3) * 16;
    const int n = n0 + row;
    float vals[16], s1 = 0.f, s2 = 0.f;
    const float* xr = x1v + (size_t)n * 64 + sg;
    #pragma unroll
    for (int e = 0; e < 16; e++) {
        float vv = Y[row][sg + e] + xr[e];
        vals[e] = vv; s1 += vv; s2 += vv * vv;
    }
    s1 += __shfl_xor(s1, 1, 4); s1 += __shfl_xor(s1, 2, 4);
    s2 += __shfl_xor(s2, 1, 4); s2 += __shfl_xor(s2, 2, 4);
    float mean = s1 * 0.015625f;
    float var = s2 * 0.015625f - mean * mean;
    float rstd = rsqrtf(var + 1e-5f);
    float* orow = outp + (size_t)n * 64;
    #pragma unroll
    for (int e = 0; e < 16; e++) {
        int c = sg + e;
        orow[c] = (vals[e] - mean) * rstd * g2[c] + be2[c];
    }
}

// ---------------------------------------------------------------------------
extern "C" void kernel_launch(void* const* d_in, const int* in_sizes, int n_in,
                              void* d_out, int out_size, void* d_ws, size_t ws_size,
                              hipStream_t stream)
{
    const float* x   = (const float*)d_in[0];
    const float* Wq  = (const float*)d_in[1];
    const float* bq  = (const float*)d_in[2];
    const float* Wk  = (const float*)d_in[3];
    const float* bk  = (const float*)d_in[4];
    const float* Wv  = (const float*)d_in[5];
    const float* bv  = (const float*)d_in[6];
    const float* Wo  = (const float*)d_in[7];
    const float* bo  = (const float*)d_in[8];
    const float* tha = (const float*)d_in[9];
    const float* thf = (const float*)d_in[10];
    const float* W1  = (const float*)d_in[11];
    const float* b1  = (const float*)d_in[12];
    const float* W2  = (const float*)d_in[13];
    const float* b2  = (const float*)d_in[14];
    const float* g1  = (const float*)d_in[15];
    const float* be1 = (const float*)d_in[16];
    const float* g2  = (const float*)d_in[17];
    const float* be2 = (const float*)d_in[18];

    // workspace layout (24 MB):
    //   [0,16M):  phase A: qb(2M) kb(2M) vb(2M) attn(4M @ +6M); phase B: hbuf(16M)
    //   [16M,20M): x1      [20M,24M): qout
    char* wsb = (char*)d_ws;
    unsigned short* qb  = (unsigned short*)(wsb);
    unsigned short* kbp = (unsigned short*)(wsb + (2u << 20));
    unsigned short* vbp = (unsigned short*)(wsb + (4u << 20));
    float* attn = (float*)(wsb + (6u << 20));
    float* hbuf = (float*)(wsb);
    float* x1   = (float*)(wsb + (16u << 20));
    float* qout = (float*)(wsb + (20u << 20));

    qkv_kernel<<<NROWS/64, 256, 0, stream>>>(x, Wq, bq, Wk, bk, Wv, bv, tha, qb, kbp, vbp);
    attn_kernel<<<64 * 32, 256, 0, stream>>>(qb, kbp, vbp, attn);
    postattn_kernel<<<NROWS/64, 256, 0, stream>>>(attn, x, Wo, bo, g1, be1, thf, x1, qout);
    ffn1_kernel<<<NROWS/64, 256, 0, stream>>>(qout, W1, b1, hbuf);
    ffn2_kernel<<<NROWS/64, 256, 0, stream>>>(hbuf, x1, W2, b2, g2, be2, (float*)d_out);
}

// Round 3
// 170.567 us; speedup vs baseline: 1.3969x; 1.3969x over previous
//
#include <hip/hip_runtime.h>
#include <hip/hip_bf16.h>

#define B_ 8
#define T_ 2048
#define NROWS 16384

typedef __attribute__((ext_vector_type(4))) float f32x4;
typedef __attribute__((ext_vector_type(16))) float f32x16;
typedef __attribute__((ext_vector_type(8))) short short8;
typedef __fp16 half2_t __attribute__((ext_vector_type(2)));

__device__ __forceinline__ unsigned short f2bf(float f) {
    __hip_bfloat16 h = __float2bfloat16(f);
    return *reinterpret_cast<unsigned short*>(&h);
}
__device__ __forceinline__ unsigned int pkrtz(float a, float b) {
    half2_t h = __builtin_amdgcn_cvt_pkrtz(a, b);
    return __builtin_bit_cast(unsigned int, h);
}
__device__ __forceinline__ float dot2(unsigned int a, unsigned int b, float c) {
    return __builtin_amdgcn_fdot2(__builtin_bit_cast(half2_t, a),
                                  __builtin_bit_cast(half2_t, b), c, false);
}
__device__ __forceinline__ float fast_exp2(float x) {
#if __has_builtin(__builtin_amdgcn_exp2f)
    return __builtin_amdgcn_exp2f(x);
#else
    return exp2f(x);
#endif
}

// ---------------------------------------------------------------------------
// Kernel 1: QKV projection via v_dot2_f32_f16 + cos(.+theta) + bf16 pack to
// [B,H,T,DK]. q scaled by log2(e)/sqrt(8) so attention uses raw exp2.
// 512 blocks x 512 threads (32 rows/block) -> 4 waves/SIMD.
// ---------------------------------------------------------------------------
__global__ __launch_bounds__(512, 4) void qkv_kernel(
    const float* __restrict__ x,
    const float* __restrict__ Wq, const float* __restrict__ bq,
    const float* __restrict__ Wk, const float* __restrict__ bk,
    const float* __restrict__ Wv, const float* __restrict__ bv,
    const float* __restrict__ theta_attn,
    unsigned short* __restrict__ qb, unsigned short* __restrict__ kbuf,
    unsigned short* __restrict__ vbuf)
{
    __shared__ unsigned int xpk[32][34];    // fp16 pairs of x^T: [kpair][row]
    __shared__ unsigned int wpk[32][196];   // fp16 pairs of W^T: [kpair][col 0..191]
    const int tid = threadIdx.x;
    const int n0 = blockIdx.x * 32;

    {   // stage x tile (32 rows x 64 k) as fp16 pairs
        float4 v = ((const float4*)(x + (size_t)n0 * 64))[tid];
        int r = tid >> 4, k0 = (tid & 15) * 4;
        xpk[(k0 >> 1) + 0][r] = pkrtz(v.x, v.y);
        xpk[(k0 >> 1) + 1][r] = pkrtz(v.z, v.w);
    }
    const float* Wm[3] = {Wq, Wk, Wv};
    #pragma unroll
    for (int t = 0; t < 6; t++) {           // 3072 float4 = 3 x (64x64)
        int fi = tid + t * 512;
        int m = fi >> 10, j = (fi >> 4) & 63, k0 = (fi & 15) * 4;
        float4 v = ((const float4*)Wm[m])[fi & 1023];
        wpk[(k0 >> 1) + 0][m * 64 + j] = pkrtz(v.x, v.y);
        wpk[(k0 >> 1) + 1][m * 64 + j] = pkrtz(v.z, v.w);
    }
    __syncthreads();

    const int r = tid >> 4;                 // 1 row per thread
    const int c0 = (tid & 15) * 12;         // 12 cols
    float acc[12] = {};
    #pragma unroll 8
    for (int kp = 0; kp < 32; kp++) {
        unsigned int a = xpk[kp][r];
        uint4 b0 = *(const uint4*)&wpk[kp][c0];
        uint4 b1 = *(const uint4*)&wpk[kp][c0 + 4];
        uint4 b2 = *(const uint4*)&wpk[kp][c0 + 8];
        unsigned int bb[12] = {b0.x, b0.y, b0.z, b0.w,
                               b1.x, b1.y, b1.z, b1.w,
                               b2.x, b2.y, b2.z, b2.w};
        #pragma unroll
        for (int j = 0; j < 12; j++) acc[j] = dot2(a, bb[j], acc[j]);
    }

    const float th = *theta_attn;
    const float QS = 0.51006980f;  // log2(e)/sqrt(8)
    const float* biasp[3] = {bq, bk, bv};
    unsigned short* outp3[3] = {qb, kbuf, vbuf};
    const int n = n0 + r;
    const int bI = n >> 11, tI = n & 2047;
    #pragma unroll
    for (int j = 0; j < 12; j++) {
        int c = c0 + j;
        int m = c >> 6, cc = c & 63;
        float val = __cosf(acc[j] + biasp[m][cc] + th);
        if (m == 0) val *= QS;
        size_t idx = ((size_t)(bI * 8 + (cc >> 3)) * 2048 + tI) * 8 + (cc & 7);
        outp3[m][idx] = f2bf(val);
    }
}

// ---------------------------------------------------------------------------
// Kernel 2: flash attention, S^T formulation with 32x32x16 bf16 MFMA.
// S^T = MFMA(A=K, B=Q): C gives col=q, row=s. P^T repacked into PV B-operand
// with 8 v_perm packs + 8 shfl_xor(32) + cndmask per 32-key chunk (no LDS
// P round-trip, no lgkmcnt(0) serializer). O^T = MFMA(A=V^T, B=P^T).
// No-max softmax is exact: |s| <= 8/sqrt(8).
// ---------------------------------------------------------------------------
__global__ __launch_bounds__(256, 4) void attn_kernel(
    const unsigned short* __restrict__ qb,
    const unsigned short* __restrict__ kbuf,
    const unsigned short* __restrict__ vbuf,
    float* __restrict__ attn)
{
    __shared__ unsigned short Ks[1024 * 8];   // K rows bf16, half of T
    __shared__ unsigned short Vt[8 * 1032];   // V^T bf16, padded stride
    const int tid = threadIdx.x;
    const int head = blockIdx.x >> 4;         // b*8 + h
    const int qblk = blockIdx.x & 15;
    const size_t hoff = (size_t)head * T_ * 8;
    const int wave = tid >> 6, lane = tid & 63;
    const int col = lane & 31, h = lane >> 5;
    const int q0 = qblk * 128 + wave * 32;

    const short8 z8 = {0, 0, 0, 0, 0, 0, 0, 0};
    short8 bqf = z8;                          // Q B-frag: n=q (lanes 0-31), k=d
    if (h == 0) bqf = *(const short8*)(qb + hoff + (size_t)(q0 + col) * 8);

    f32x16 oacc = {0.f,0.f,0.f,0.f,0.f,0.f,0.f,0.f,0.f,0.f,0.f,0.f,0.f,0.f,0.f,0.f};
    const f32x16 z16 = {0.f,0.f,0.f,0.f,0.f,0.f,0.f,0.f,0.f,0.f,0.f,0.f,0.f,0.f,0.f,0.f};
    float lsum = 0.f;

    for (int half = 0; half < 2; half++) {
        __syncthreads();
        {
            const uint4* kg = (const uint4*)(kbuf + hoff + (size_t)half * 1024 * 8);
            const uint4* vg = (const uint4*)(vbuf + hoff + (size_t)half * 1024 * 8);
            uint4* kl = (uint4*)Ks;
            #pragma unroll
            for (int it = 0; it < 4; it++) {
                int s = tid + it * 256;
                kl[s] = kg[s];
                union { uint4 u; unsigned short us[8]; } cv;
                cv.u = vg[s];
                #pragma unroll
                for (int d = 0; d < 8; d++) Vt[d * 1032 + s] = cv.us[d];
            }
        }
        __syncthreads();

        for (int s0 = 0; s0 < 1024; s0 += 32) {
            short8 ak = z8;                   // K A-frag: m=key, k=d
            if (h == 0) ak = *(const short8*)&Ks[(s0 + col) * 8];
            f32x16 S = __builtin_amdgcn_mfma_f32_32x32x16_bf16(ak, bqf, z16, 0, 0, 0);
            float p[16];
            #pragma unroll
            for (int rr = 0; rr < 16; rr++) {
                p[rr] = fast_exp2(S[rr]);
                lsum += p[rr];
            }
            #pragma unroll
            for (int g = 0; g < 2; g++) {     // keys [s0+16g, s0+16g+16)
                const float* pp = p + g * 8;
                unsigned int q01 = __builtin_amdgcn_perm(__float_as_uint(pp[1]), __float_as_uint(pp[0]), 0x07060302u);
                unsigned int q23 = __builtin_amdgcn_perm(__float_as_uint(pp[3]), __float_as_uint(pp[2]), 0x07060302u);
                unsigned int q45 = __builtin_amdgcn_perm(__float_as_uint(pp[5]), __float_as_uint(pp[4]), 0x07060302u);
                unsigned int q67 = __builtin_amdgcn_perm(__float_as_uint(pp[7]), __float_as_uint(pp[6]), 0x07060302u);
                unsigned int x01 = (unsigned int)__shfl_xor((int)q01, 32);
                unsigned int x23 = (unsigned int)__shfl_xor((int)q23, 32);
                unsigned int x45 = (unsigned int)__shfl_xor((int)q45, 32);
                unsigned int x67 = (unsigned int)__shfl_xor((int)q67, 32);
                union { unsigned int u[4]; short8 s; } bp;
                bp.u[0] = h ? x45 : q01;
                bp.u[1] = h ? x67 : q23;
                bp.u[2] = h ? q45 : x01;
                bp.u[3] = h ? q67 : x23;
                short8 av = z8;               // V^T A-frag: m=d, k=s-local
                if (col < 8) av = *(const short8*)&Vt[col * 1032 + s0 + g * 16 + 8 * h];
                oacc = __builtin_amdgcn_mfma_f32_32x32x16_bf16(av, bp.s, oacc, 0, 0, 0);
            }
        }
    }

    lsum += __shfl_xor(lsum, 32);             // this lane held half the s-range
    const float inv = 1.0f / lsum;
    const int bI = head >> 3, hI = head & 7;
    const int q = q0 + col;
    #pragma unroll
    for (int rr = 0; rr < 4; rr++) {          // O^T regs 0-3: d = 4h + rr
        int d = 4 * h + rr;
        attn[((size_t)bI * 2048 + q) * 64 + hI * 8 + d] = oacc[rr] * inv;
    }
}

// ---------------------------------------------------------------------------
// Kernel 3 (fused tail): y=attn@Wo^T+bo; x1=LN(x+y); qout=cos(x1)cos(thf);
// h=relu(qout@W1^T+b1); f=h@W2^T+b2; out=LN(x1+f).  All GEMMs via
// v_dot2_f32_f16 on fp16-pair packed LDS. x1 lives in registers; qout/h in
// LDS; weight buffers share one region staged phase-by-phase.
// 256 blocks x 512 threads (64 rows/block).
// ---------------------------------------------------------------------------
__global__ __launch_bounds__(512, 4) void tail_kernel(
    const float* __restrict__ attn, const float* __restrict__ x,
    const float* __restrict__ Wo, const float* __restrict__ bo,
    const float* __restrict__ g1, const float* __restrict__ be1,
    const float* __restrict__ theta_ffn,
    const float* __restrict__ W1, const float* __restrict__ b1,
    const float* __restrict__ W2, const float* __restrict__ b2,
    const float* __restrict__ g2, const float* __restrict__ be2,
    float* __restrict__ outp)
{
    __shared__ unsigned int Wbuf[8704];     // Wopk 32x68 | W1pk 32x260 | W2pk 128x68
    __shared__ unsigned int qpk[32 * 66];   // qout fp16 pairs [kpair][row]
    __shared__ unsigned int Upk[128 * 66];  // Atpk 32x66 then hpk 128x66
    const int tid = threadIdx.x;
    const int n0 = blockIdx.x * 64;
    const int r0 = (tid >> 4) * 2;          // GEMM1/3 mapping: 2 rows
    const int c0 = (tid & 15) * 4;          // x 4 cols

    // ---- stage At (fp16 pairs, [kpair][row]) + Wopk ----
    {
        const float4* ag = (const float4*)(attn + (size_t)n0 * 64);
        #pragma unroll
        for (int t = 0; t < 2; t++) {
            int fi = tid + t * 512;         // 1024 float4 = 64x64
            float4 v = ag[fi];
            int rr = fi >> 4, k0 = (fi & 15) * 4;
            Upk[((k0 >> 1) + 0) * 66 + rr] = pkrtz(v.x, v.y);
            Upk[((k0 >> 1) + 1) * 66 + rr] = pkrtz(v.z, v.w);
        }
        #pragma unroll
        for (int t = 0; t < 2; t++) {
            int fi = tid + t * 512;
            float4 v = ((const float4*)Wo)[fi];
            int nn = fi >> 4, k0 = (fi & 15) * 4;
            Wbuf[((k0 >> 1) + 0) * 68 + nn] = pkrtz(v.x, v.y);
            Wbuf[((k0 >> 1) + 1) * 68 + nn] = pkrtz(v.z, v.w);
        }
    }
    __syncthreads();

    // ---- GEMM1: y = At @ Wo^T ----
    float acc1[2][4] = {};
    #pragma unroll 8
    for (int kp = 0; kp < 32; kp++) {
        unsigned int a0 = Upk[kp * 66 + r0];
        unsigned int a1 = Upk[kp * 66 + r0 + 1];
        uint4 b = *(const uint4*)&Wbuf[kp * 68 + c0];
        unsigned int bb[4] = {b.x, b.y, b.z, b.w};
        #pragma unroll
        for (int j = 0; j < 4; j++) {
            acc1[0][j] = dot2(a0, bb[j], acc1[0][j]);
            acc1[1][j] = dot2(a1, bb[j], acc1[1][j]);
        }
    }

    // ---- ep1: x1 = LN(x + y) (regs); qout = cos(x1)*cos(thf) -> qpk ----
    float x1v[2][4];
    {
        float4 bo4 = *(const float4*)&bo[c0];
        float4 g14 = *(const float4*)&g1[c0];
        float4 be14 = *(const float4*)&be1[c0];
        float gg[4] = {g14.x, g14.y, g14.z, g14.w};
        float eb[4] = {be14.x, be14.y, be14.z, be14.w};
        float bb[4] = {bo4.x, bo4.y, bo4.z, bo4.w};
        float cth = __cosf(*theta_ffn);
        #pragma unroll
        for (int i = 0; i < 2; i++) {
            float4 xv = *(const float4*)(x + (size_t)(n0 + r0 + i) * 64 + c0);
            float vv[4] = {xv.x + acc1[i][0] + bb[0], xv.y + acc1[i][1] + bb[1],
                           xv.z + acc1[i][2] + bb[2], xv.w + acc1[i][3] + bb[3]};
            float s1 = vv[0] + vv[1] + vv[2] + vv[3];
            float s2 = vv[0]*vv[0] + vv[1]*vv[1] + vv[2]*vv[2] + vv[3]*vv[3];
            #pragma unroll
            for (int m = 1; m <= 8; m <<= 1) {
                s1 += __shfl_xor(s1, m, 16);
                s2 += __shfl_xor(s2, m, 16);
            }
            float mean = s1 * 0.015625f;
            float rstd = rsqrtf(s2 * 0.015625f - mean * mean + 1e-5f);
            float qv[4];
            #pragma unroll
            for (int j = 0; j < 4; j++) {
                x1v[i][j] = (vv[j] - mean) * rstd * gg[j] + eb[j];
                qv[j] = __cosf(x1v[i][j]) * cth;
            }
            qpk[((c0 >> 1) + 0) * 66 + r0 + i] = pkrtz(qv[0], qv[1]);
            qpk[((c0 >> 1) + 1) * 66 + r0 + i] = pkrtz(qv[2], qv[3]);
        }
    }
    __syncthreads();

    // ---- stage W1pk [kpair][f] stride 260 ----
    #pragma unroll
    for (int t = 0; t < 8; t++) {
        int fi = tid + t * 512;             // 4096 float4 = 256x64
        float4 v = ((const float4*)W1)[fi];
        int f = fi >> 4, k0 = (fi & 15) * 4;
        Wbuf[((k0 >> 1) + 0) * 260 + f] = pkrtz(v.x, v.y);
        Wbuf[((k0 >> 1) + 1) * 260 + f] = pkrtz(v.z, v.w);
    }
    __syncthreads();

    // ---- GEMM2: h = relu(qout @ W1^T + b1) -> hpk ----
    const int r2 = (tid >> 5) * 4;          // 4 rows
    const int f0 = (tid & 31) * 8;          // x 8 cols
    float acc2[4][8] = {};
    #pragma unroll 4
    for (int kp = 0; kp < 32; kp++) {
        unsigned int a_[4];
        #pragma unroll
        for (int i = 0; i < 4; i++) a_[i] = qpk[kp * 66 + r2 + i];
        uint4 b0 = *(const uint4*)&Wbuf[kp * 260 + f0];
        uint4 b1_ = *(const uint4*)&Wbuf[kp * 260 + f0 + 4];
        unsigned int bb[8] = {b0.x, b0.y, b0.z, b0.w, b1_.x, b1_.y, b1_.z, b1_.w};
        #pragma unroll
        for (int i = 0; i < 4; i++)
            #pragma unroll
            for (int j = 0; j < 8; j++)
                acc2[i][j] = dot2(a_[i], bb[j], acc2[i][j]);
    }
    {
        float4 c1a = *(const float4*)&b1[f0];
        float4 c1b = *(const float4*)&b1[f0 + 4];
        float bb[8] = {c1a.x, c1a.y, c1a.z, c1a.w, c1b.x, c1b.y, c1b.z, c1b.w};
        #pragma unroll
        for (int i = 0; i < 4; i++) {
            float hv[8];
            #pragma unroll
            for (int j = 0; j < 8; j++) hv[j] = fmaxf(acc2[i][j] + bb[j], 0.f);
            #pragma unroll
            for (int jp = 0; jp < 4; jp++)
                Upk[(f0 / 2 + jp) * 66 + r2 + i] = pkrtz(hv[2 * jp], hv[2 * jp + 1]);
        }
    }
    __syncthreads();

    // ---- stage W2pk [fpair][e] stride 68 ----
    #pragma unroll
    for (int t = 0; t < 8; t++) {
        int fi = tid + t * 512;             // 4096 float4 = 64x256
        float4 v = ((const float4*)W2)[fi];
        int e = fi >> 6, k0 = (fi & 63) * 4;
        Wbuf[((k0 >> 1) + 0) * 68 + e] = pkrtz(v.x, v.y);
        Wbuf[((k0 >> 1) + 1) * 68 + e] = pkrtz(v.z, v.w);
    }
    __syncthreads();

    // ---- GEMM3: f = h @ W2^T ----
    float acc3[2][4] = {};
    #pragma unroll 8
    for (int fp = 0; fp < 128; fp++) {
        unsigned int a0 = Upk[fp * 66 + r0];
        unsigned int a1 = Upk[fp * 66 + r0 + 1];
        uint4 b = *(const uint4*)&Wbuf[fp * 68 + c0];
        unsigned int bb[4] = {b.x, b.y, b.z, b.w};
        #pragma unroll
        for (int j = 0; j < 4; j++) {
            acc3[0][j] = dot2(a0, bb[j], acc3[0][j]);
            acc3[1][j] = dot2(a1, bb[j], acc3[1][j]);
        }
    }

    // ---- ep3: out = LN(x1 + f + b2) * g2 + be2 ----
    {
        float4 b24 = *(const float4*)&b2[c0];
        float4 g24 = *(const float4*)&g2[c0];
        float4 be24 = *(const float4*)&be2[c0];
        float bb[4] = {b24.x, b24.y, b24.z, b24.w};
        float gg[4] = {g24.x, g24.y, g24.z, g24.w};
        float eb[4] = {be24.x, be24.y, be24.z, be24.w};
        #pragma unroll
        for (int i = 0; i < 2; i++) {
            float vv[4];
            #pragma unroll
            for (int j = 0; j < 4; j++) vv[j] = x1v[i][j] + acc3[i][j] + bb[j];
            float s1 = vv[0] + vv[1] + vv[2] + vv[3];
            float s2 = vv[0]*vv[0] + vv[1]*vv[1] + vv[2]*vv[2] + vv[3]*vv[3];
            #pragma unroll
            for (int m = 1; m <= 8; m <<= 1) {
                s1 += __shfl_xor(s1, m, 16);
                s2 += __shfl_xor(s2, m, 16);
            }
            float mean = s1 * 0.015625f;
            float rstd = rsqrtf(s2 * 0.015625f - mean * mean + 1e-5f);
            float4 o;
            o.x = (vv[0] - mean) * rstd * gg[0] + eb[0];
            o.y = (vv[1] - mean) * rstd * gg[1] + eb[1];
            o.z = (vv[2] - mean) * rstd * gg[2] + eb[2];
            o.w = (vv[3] - mean) * rstd * gg[3] + eb[3];
            *(float4*)(outp + (size_t)(n0 + r0 + i) * 64 + c0) = o;
        }
    }
}

// ---------------------------------------------------------------------------
extern "C" void kernel_launch(void* const* d_in, const int* in_sizes, int n_in,
                              void* d_out, int out_size, void* d_ws, size_t ws_size,
                              hipStream_t stream)
{
    const float* x   = (const float*)d_in[0];
    const float* Wq  = (const float*)d_in[1];
    const float* bq  = (const float*)d_in[2];
    const float* Wk  = (const float*)d_in[3];
    const float* bk  = (const float*)d_in[4];
    const float* Wv  = (const float*)d_in[5];
    const float* bv  = (const float*)d_in[6];
    const float* Wo  = (const float*)d_in[7];
    const float* bo  = (const float*)d_in[8];
    const float* tha = (const float*)d_in[9];
    const float* thf = (const float*)d_in[10];
    const float* W1  = (const float*)d_in[11];
    const float* b1  = (const float*)d_in[12];
    const float* W2  = (const float*)d_in[13];
    const float* b2  = (const float*)d_in[14];
    const float* g1  = (const float*)d_in[15];
    const float* be1 = (const float*)d_in[16];
    const float* g2  = (const float*)d_in[17];
    const float* be2 = (const float*)d_in[18];

    // workspace: qb(2M) kb(2M) vb(2M) attn(4M)
    char* wsb = (char*)d_ws;
    unsigned short* qbp = (unsigned short*)(wsb);
    unsigned short* kbp = (unsigned short*)(wsb + (2u << 20));
    unsigned short* vbp = (unsigned short*)(wsb + (4u << 20));
    float* attn = (float*)(wsb + (6u << 20));

    qkv_kernel<<<512, 512, 0, stream>>>(x, Wq, bq, Wk, bk, Wv, bv, tha, qbp, kbp, vbp);
    attn_kernel<<<1024, 256, 0, stream>>>(qbp, kbp, vbp, attn);
    tail_kernel<<<256, 512, 0, stream>>>(attn, x, Wo, bo, g1, be1, thf,
                                         W1, b1, W2, b2, g2, be2, (float*)d_out);
}

// Round 4
// 165.425 us; speedup vs baseline: 1.4403x; 1.0311x over previous
//
#include <hip/hip_runtime.h>
#include <hip/hip_bf16.h>

#define B_ 8
#define T_ 2048
#define NROWS 16384

typedef __attribute__((ext_vector_type(4))) float f32x4;
typedef __attribute__((ext_vector_type(16))) float f32x16;
typedef __attribute__((ext_vector_type(8))) short short8;
typedef __fp16 half2_t __attribute__((ext_vector_type(2)));

__device__ __forceinline__ unsigned short f2bf(float f) {
    __hip_bfloat16 h = __float2bfloat16(f);
    return *reinterpret_cast<unsigned short*>(&h);
}
__device__ __forceinline__ unsigned int pkrtz(float a, float b) {
    half2_t h = __builtin_amdgcn_cvt_pkrtz(a, b);
    return __builtin_bit_cast(unsigned int, h);
}
__device__ __forceinline__ float dot2(unsigned int a, unsigned int b, float c) {
    return __builtin_amdgcn_fdot2(__builtin_bit_cast(half2_t, a),
                                  __builtin_bit_cast(half2_t, b), c, false);
}
__device__ __forceinline__ float fast_exp2(float x) {
#if __has_builtin(__builtin_amdgcn_exp2f)
    return __builtin_amdgcn_exp2f(x);
#else
    return exp2f(x);
#endif
}

// ---------------------------------------------------------------------------
// Kernel 1: QKV projection via v_dot2_f32_f16 + cos(.+theta). Results go
// through an LDS tile in OUTPUT layout so global stores are coalesced uint4
// (previous version did 12 scattered 2-byte stores/thread with per-lane base
// pointer select -- the main cost). q scaled by log2(e)/sqrt(8).
// ---------------------------------------------------------------------------
__global__ __launch_bounds__(512, 4) void qkv_kernel(
    const float* __restrict__ x,
    const float* __restrict__ Wq, const float* __restrict__ bq,
    const float* __restrict__ Wk, const float* __restrict__ bk,
    const float* __restrict__ Wv, const float* __restrict__ bv,
    const float* __restrict__ theta_attn,
    unsigned short* __restrict__ qb, unsigned short* __restrict__ kbuf,
    unsigned short* __restrict__ vbuf)
{
    __shared__ unsigned int xpk[32][34];      // fp16 pairs of x^T: [kpair][row]
    __shared__ unsigned int wpk[32][196];     // fp16 pairs of W^T: [kpair][col]
    __shared__ unsigned short outs[32][216];  // bf16 results [row][col], 16B-aligned rows
    const int tid = threadIdx.x;
    const int n0 = blockIdx.x * 32;

    {   // stage x tile (32 rows x 64 k) as fp16 pairs
        float4 v = ((const float4*)(x + (size_t)n0 * 64))[tid];
        int r = tid >> 4, k0 = (tid & 15) * 4;
        xpk[(k0 >> 1) + 0][r] = pkrtz(v.x, v.y);
        xpk[(k0 >> 1) + 1][r] = pkrtz(v.z, v.w);
    }
    const float* Wm[3] = {Wq, Wk, Wv};
    #pragma unroll
    for (int t = 0; t < 6; t++) {             // 3072 float4 = 3 x (64x64)
        int fi = tid + t * 512;
        int m = fi >> 10, j = (fi >> 4) & 63, k0 = (fi & 15) * 4;
        float4 v = ((const float4*)Wm[m])[fi & 1023];
        wpk[(k0 >> 1) + 0][m * 64 + j] = pkrtz(v.x, v.y);
        wpk[(k0 >> 1) + 1][m * 64 + j] = pkrtz(v.z, v.w);
    }
    __syncthreads();

    const int r = tid >> 4;                   // 1 row per thread
    const int c0 = (tid & 15) * 12;           // 12 cols
    float acc[12] = {};
    #pragma unroll 8
    for (int kp = 0; kp < 32; kp++) {
        unsigned int a = xpk[kp][r];
        uint4 b0 = *(const uint4*)&wpk[kp][c0];
        uint4 b1 = *(const uint4*)&wpk[kp][c0 + 4];
        uint4 b2 = *(const uint4*)&wpk[kp][c0 + 8];
        unsigned int bb[12] = {b0.x, b0.y, b0.z, b0.w,
                               b1.x, b1.y, b1.z, b1.w,
                               b2.x, b2.y, b2.z, b2.w};
        #pragma unroll
        for (int j = 0; j < 12; j++) acc[j] = dot2(a, bb[j], acc[j]);
    }

    const float th = *theta_attn;
    const float QS = 0.51006980f;  // log2(e)/sqrt(8)
    const float* biasp[3] = {bq, bk, bv};
    {
        float vals[12];
        #pragma unroll
        for (int j = 0; j < 12; j++) {
            int c = c0 + j;
            int m = c >> 6, cc = c & 63;
            float v = __cosf(acc[j] + biasp[m][cc] + th);
            vals[j] = (m == 0) ? v * QS : v;
        }
        unsigned int* orow = (unsigned int*)&outs[r][c0];   // 24B offset: dword-aligned
        #pragma unroll
        for (int jp = 0; jp < 6; jp++)
            orow[jp] = (unsigned int)f2bf(vals[2 * jp]) |
                       ((unsigned int)f2bf(vals[2 * jp + 1]) << 16);
    }
    __syncthreads();

    // coalesced stores: one uint4 (= 8 bf16 = full d-row of one head) per unit
    unsigned short* outp3[3] = {qb, kbuf, vbuf};
    #pragma unroll
    for (int t = 0; t < 2; t++) {
        int fi = tid + t * 512;
        if (fi < 768) {                       // wave-uniform predicate
            int m = fi >> 8, rest = fi & 255;
            int hI = rest >> 5, r2 = rest & 31;
            uint4 v = *(const uint4*)&outs[r2][m * 64 + hI * 8];
            int n = n0 + r2;
            unsigned short* dst = outp3[m] +
                ((size_t)((n >> 11) * 8 + hI) * 2048 + (n & 2047)) * 8;
            *(uint4*)dst = v;
        }
    }
}

// ---------------------------------------------------------------------------
// Kernel 2: flash attention, S^T formulation with 32x32x16 bf16 MFMA.
// (unchanged from round 3: 53 us, 0 bank conflicts)
// ---------------------------------------------------------------------------
__global__ __launch_bounds__(256, 4) void attn_kernel(
    const unsigned short* __restrict__ qb,
    const unsigned short* __restrict__ kbuf,
    const unsigned short* __restrict__ vbuf,
    float* __restrict__ attn)
{
    __shared__ unsigned short Ks[1024 * 8];   // K rows bf16, half of T
    __shared__ unsigned short Vt[8 * 1032];   // V^T bf16, padded stride
    const int tid = threadIdx.x;
    const int head = blockIdx.x >> 4;         // b*8 + h
    const int qblk = blockIdx.x & 15;
    const size_t hoff = (size_t)head * T_ * 8;
    const int wave = tid >> 6, lane = tid & 63;
    const int col = lane & 31, h = lane >> 5;
    const int q0 = qblk * 128 + wave * 32;

    const short8 z8 = {0, 0, 0, 0, 0, 0, 0, 0};
    short8 bqf = z8;                          // Q B-frag: n=q (lanes 0-31), k=d
    if (h == 0) bqf = *(const short8*)(qb + hoff + (size_t)(q0 + col) * 8);

    f32x16 oacc = {0.f,0.f,0.f,0.f,0.f,0.f,0.f,0.f,0.f,0.f,0.f,0.f,0.f,0.f,0.f,0.f};
    const f32x16 z16 = {0.f,0.f,0.f,0.f,0.f,0.f,0.f,0.f,0.f,0.f,0.f,0.f,0.f,0.f,0.f,0.f};
    float lsum = 0.f;

    for (int half = 0; half < 2; half++) {
        __syncthreads();
        {
            const uint4* kg = (const uint4*)(kbuf + hoff + (size_t)half * 1024 * 8);
            const uint4* vg = (const uint4*)(vbuf + hoff + (size_t)half * 1024 * 8);
            uint4* kl = (uint4*)Ks;
            #pragma unroll
            for (int it = 0; it < 4; it++) {
                int s = tid + it * 256;
                kl[s] = kg[s];
                union { uint4 u; unsigned short us[8]; } cv;
                cv.u = vg[s];
                #pragma unroll
                for (int d = 0; d < 8; d++) Vt[d * 1032 + s] = cv.us[d];
            }
        }
        __syncthreads();

        for (int s0 = 0; s0 < 1024; s0 += 32) {
            short8 ak = z8;                   // K A-frag: m=key, k=d
            if (h == 0) ak = *(const short8*)&Ks[(s0 + col) * 8];
            f32x16 S = __builtin_amdgcn_mfma_f32_32x32x16_bf16(ak, bqf, z16, 0, 0, 0);
            float p[16];
            #pragma unroll
            for (int rr = 0; rr < 16; rr++) {
                p[rr] = fast_exp2(S[rr]);
                lsum += p[rr];
            }
            #pragma unroll
            for (int g = 0; g < 2; g++) {     // keys [s0+16g, s0+16g+16)
                const float* pp = p + g * 8;
                unsigned int q01 = __builtin_amdgcn_perm(__float_as_uint(pp[1]), __float_as_uint(pp[0]), 0x07060302u);
                unsigned int q23 = __builtin_amdgcn_perm(__float_as_uint(pp[3]), __float_as_uint(pp[2]), 0x07060302u);
                unsigned int q45 = __builtin_amdgcn_perm(__float_as_uint(pp[5]), __float_as_uint(pp[4]), 0x07060302u);
                unsigned int q67 = __builtin_amdgcn_perm(__float_as_uint(pp[7]), __float_as_uint(pp[6]), 0x07060302u);
                unsigned int x01 = (unsigned int)__shfl_xor((int)q01, 32);
                unsigned int x23 = (unsigned int)__shfl_xor((int)q23, 32);
                unsigned int x45 = (unsigned int)__shfl_xor((int)q45, 32);
                unsigned int x67 = (unsigned int)__shfl_xor((int)q67, 32);
                union { unsigned int u[4]; short8 s; } bp;
                bp.u[0] = h ? x45 : q01;
                bp.u[1] = h ? x67 : q23;
                bp.u[2] = h ? q45 : x01;
                bp.u[3] = h ? q67 : x23;
                short8 av = z8;               // V^T A-frag: m=d, k=s-local
                if (col < 8) av = *(const short8*)&Vt[col * 1032 + s0 + g * 16 + 8 * h];
                oacc = __builtin_amdgcn_mfma_f32_32x32x16_bf16(av, bp.s, oacc, 0, 0, 0);
            }
        }
    }

    lsum += __shfl_xor(lsum, 32);             // this lane held half the s-range
    const float inv = 1.0f / lsum;
    const int bI = head >> 3, hI = head & 7;
    const int q = q0 + col;
    #pragma unroll
    for (int rr = 0; rr < 4; rr++) {          // O^T regs 0-3: d = 4h + rr
        int d = 4 * h + rr;
        attn[((size_t)bI * 2048 + q) * 64 + hI * 8 + d] = oacc[rr] * inv;
    }
}

// ---------------------------------------------------------------------------
// Kernel 3 (fused tail): y=attn@Wo^T+bo; x1=LN(x+y); qout=cos(x1)cos(thf);
// h=relu(qout@W1^T+b1); f=h@W2^T+b2; out=LN(x1+f).
// 32-row tiles (512 blocks x 512 thr) + software-pipelined weight prefetch:
// W1/W2 global loads are issued into registers BEFORE the preceding GEMM so
// their HBM/L2 latency overlaps compute (issue order: small ops first so
// early vmcnt waits don't drain the prefetch queue).
// ---------------------------------------------------------------------------
__global__ __launch_bounds__(512, 4) void tail_kernel(
    const float* __restrict__ attn, const float* __restrict__ x,
    const float* __restrict__ Wo, const float* __restrict__ bo,
    const float* __restrict__ g1, const float* __restrict__ be1,
    const float* __restrict__ theta_ffn,
    const float* __restrict__ W1, const float* __restrict__ b1,
    const float* __restrict__ W2, const float* __restrict__ b2,
    const float* __restrict__ g2, const float* __restrict__ be2,
    float* __restrict__ outp)
{
    __shared__ unsigned int Wbuf[10880];    // [0,2176): Wopk 32x68 | [2176,+): W1pk 32x260 / W2pk 128x68
    __shared__ unsigned int qpk[32 * 34];   // qout fp16 pairs [kpair][row]
    __shared__ unsigned int Upk[128 * 34];  // At pairs 32x34, then h pairs 128x34
    const int tid = threadIdx.x;
    const int n0 = blockIdx.x * 32;
    const int r0 = tid >> 4;                // row 0..31 (GEMM1/3)
    const int c0 = (tid & 15) * 4;          // col
    unsigned int* const W1p = Wbuf + 2176;
    unsigned int* const W2p = Wbuf + 2176;

    // ---- early issues: consumed-soon loads first, then W1 prefetch ----
    float4 atv = ((const float4*)(attn + (size_t)n0 * 64))[tid];
    float4 wo0 = ((const float4*)Wo)[tid];
    float4 wo1 = ((const float4*)Wo)[tid + 512];
    float4 xv  = *(const float4*)(x + (size_t)(n0 + r0) * 64 + c0);
    float4 w1r[8];
    #pragma unroll
    for (int t = 0; t < 8; t++) w1r[t] = ((const float4*)W1)[tid + t * 512];

    // ---- stage At + Wo (waits only their vmcnt slots; W1 stays in flight) ----
    {
        int rr = tid >> 4, k0 = (tid & 15) * 4;
        Upk[((k0 >> 1) + 0) * 34 + rr] = pkrtz(atv.x, atv.y);
        Upk[((k0 >> 1) + 1) * 34 + rr] = pkrtz(atv.z, atv.w);
    }
    {
        int nn = tid >> 4, k0 = (tid & 15) * 4;
        Wbuf[((k0 >> 1) + 0) * 68 + nn] = pkrtz(wo0.x, wo0.y);
        Wbuf[((k0 >> 1) + 1) * 68 + nn] = pkrtz(wo0.z, wo0.w);
        int fi = tid + 512;
        nn = fi >> 4; k0 = (fi & 15) * 4;
        Wbuf[((k0 >> 1) + 0) * 68 + nn] = pkrtz(wo1.x, wo1.y);
        Wbuf[((k0 >> 1) + 1) * 68 + nn] = pkrtz(wo1.z, wo1.w);
    }
    __syncthreads();

    // ---- W1 -> private LDS region (no hazard with GEMM1 reads) ----
    #pragma unroll
    for (int t = 0; t < 8; t++) {
        int fi = tid + t * 512;               // 4096 float4 = 256x64
        int f = fi >> 4, k0 = (fi & 15) * 4;
        W1p[((k0 >> 1) + 0) * 260 + f] = pkrtz(w1r[t].x, w1r[t].y);
        W1p[((k0 >> 1) + 1) * 260 + f] = pkrtz(w1r[t].z, w1r[t].w);
    }

    // ---- GEMM1: y = At @ Wo^T (1 row x 4 cols per thread) ----
    float acc1[4] = {};
    #pragma unroll 8
    for (int kp = 0; kp < 32; kp++) {
        unsigned int a = Upk[kp * 34 + r0];
        uint4 b = *(const uint4*)&Wbuf[kp * 68 + c0];
        acc1[0] = dot2(a, b.x, acc1[0]);
        acc1[1] = dot2(a, b.y, acc1[1]);
        acc1[2] = dot2(a, b.z, acc1[2]);
        acc1[3] = dot2(a, b.w, acc1[3]);
    }

    // ---- ep1: x1 = LN(x+y+bo) (regs); qout = cos(x1)*cos(thf) -> qpk ----
    float x1v[4];
    {
        float4 bo4 = *(const float4*)&bo[c0];
        float4 g14 = *(const float4*)&g1[c0];
        float4 be14 = *(const float4*)&be1[c0];
        float cth = __cosf(*theta_ffn);
        float vv[4] = {xv.x + acc1[0] + bo4.x, xv.y + acc1[1] + bo4.y,
                       xv.z + acc1[2] + bo4.z, xv.w + acc1[3] + bo4.w};
        float s1 = vv[0] + vv[1] + vv[2] + vv[3];
        float s2 = vv[0]*vv[0] + vv[1]*vv[1] + vv[2]*vv[2] + vv[3]*vv[3];
        #pragma unroll
        for (int m = 1; m <= 8; m <<= 1) {
            s1 += __shfl_xor(s1, m, 16);
            s2 += __shfl_xor(s2, m, 16);
        }
        float mean = s1 * 0.015625f;
        float rstd = rsqrtf(s2 * 0.015625f - mean * mean + 1e-5f);
        float gg[4] = {g14.x, g14.y, g14.z, g14.w};
        float eb[4] = {be14.x, be14.y, be14.z, be14.w};
        float qv[4];
        #pragma unroll
        for (int j = 0; j < 4; j++) {
            x1v[j] = (vv[j] - mean) * rstd * gg[j] + eb[j];
            qv[j] = __cosf(x1v[j]) * cth;
        }
        qpk[((c0 >> 1) + 0) * 34 + r0] = pkrtz(qv[0], qv[1]);
        qpk[((c0 >> 1) + 1) * 34 + r0] = pkrtz(qv[2], qv[3]);
    }
    __syncthreads();

    // ---- W2 prefetch (in flight across GEMM2) ----
    float4 w2r[8];
    #pragma unroll
    for (int t = 0; t < 8; t++) w2r[t] = ((const float4*)W2)[tid + t * 512];

    // ---- GEMM2: h = relu(qout @ W1^T + b1) -> Upk (2 rows x 8 f) ----
    const int r2 = (tid >> 5) * 2;
    const int f0 = (tid & 31) * 8;
    float acc2[2][8] = {};
    #pragma unroll 4
    for (int kp = 0; kp < 32; kp++) {
        unsigned int a0 = qpk[kp * 34 + r2];
        unsigned int a1 = qpk[kp * 34 + r2 + 1];
        uint4 b0 = *(const uint4*)&W1p[kp * 260 + f0];
        uint4 b1_ = *(const uint4*)&W1p[kp * 260 + f0 + 4];
        unsigned int bb[8] = {b0.x, b0.y, b0.z, b0.w, b1_.x, b1_.y, b1_.z, b1_.w};
        #pragma unroll
        for (int j = 0; j < 8; j++) {
            acc2[0][j] = dot2(a0, bb[j], acc2[0][j]);
            acc2[1][j] = dot2(a1, bb[j], acc2[1][j]);
        }
    }
    {
        float4 c1a = *(const float4*)&b1[f0];
        float4 c1b = *(const float4*)&b1[f0 + 4];
        float bb[8] = {c1a.x, c1a.y, c1a.z, c1a.w, c1b.x, c1b.y, c1b.z, c1b.w};
        #pragma unroll
        for (int i = 0; i < 2; i++) {
            float hv[8];
            #pragma unroll
            for (int j = 0; j < 8; j++) hv[j] = fmaxf(acc2[i][j] + bb[j], 0.f);
            #pragma unroll
            for (int jp = 0; jp < 4; jp++)
                Upk[(f0 / 2 + jp) * 34 + r2 + i] = pkrtz(hv[2 * jp], hv[2 * jp + 1]);
        }
    }
    __syncthreads();

    // ---- W2 regs -> LDS (overwrites W1 region; GEMM2 done reading it) ----
    #pragma unroll
    for (int t = 0; t < 8; t++) {
        int fi = tid + t * 512;               // 4096 float4 = 64 e x 64 fgroups
        int e = fi >> 6, k0 = (fi & 63) * 4;
        W2p[((k0 >> 1) + 0) * 68 + e] = pkrtz(w2r[t].x, w2r[t].y);
        W2p[((k0 >> 1) + 1) * 68 + e] = pkrtz(w2r[t].z, w2r[t].w);
    }
    __syncthreads();

    // ---- GEMM3: f = h @ W2^T (1 row x 4 cols per thread) ----
    float acc3[4] = {};
    #pragma unroll 8
    for (int fp = 0; fp < 128; fp++) {
        unsigned int a = Upk[fp * 34 + r0];
        uint4 b = *(const uint4*)&W2p[fp * 68 + c0];
        acc3[0] = dot2(a, b.x, acc3[0]);
        acc3[1] = dot2(a, b.y, acc3[1]);
        acc3[2] = dot2(a, b.z, acc3[2]);
        acc3[3] = dot2(a, b.w, acc3[3]);
    }

    // ---- ep3: out = LN(x1 + f + b2) * g2 + be2 ----
    {
        float4 b24 = *(const float4*)&b2[c0];
        float4 g24 = *(const float4*)&g2[c0];
        float4 be24 = *(const float4*)&be2[c0];
        float vv[4] = {x1v[0] + acc3[0] + b24.x, x1v[1] + acc3[1] + b24.y,
                       x1v[2] + acc3[2] + b24.z, x1v[3] + acc3[3] + b24.w};
        float s1 = vv[0] + vv[1] + vv[2] + vv[3];
        float s2 = vv[0]*vv[0] + vv[1]*vv[1] + vv[2]*vv[2] + vv[3]*vv[3];
        #pragma unroll
        for (int m = 1; m <= 8; m <<= 1) {
            s1 += __shfl_xor(s1, m, 16);
            s2 += __shfl_xor(s2, m, 16);
        }
        float mean = s1 * 0.015625f;
        float rstd = rsqrtf(s2 * 0.015625f - mean * mean + 1e-5f);
        float4 o;
        o.x = (vv[0] - mean) * rstd * g24.x + be24.x;
        o.y = (vv[1] - mean) * rstd * g24.y + be24.y;
        o.z = (vv[2] - mean) * rstd * g24.z + be24.z;
        o.w = (vv[3] - mean) * rstd * g24.w + be24.w;
        *(float4*)(outp + (size_t)(n0 + r0) * 64 + c0) = o;
    }
}

// ---------------------------------------------------------------------------
extern "C" void kernel_launch(void* const* d_in, const int* in_sizes, int n_in,
                              void* d_out, int out_size, void* d_ws, size_t ws_size,
                              hipStream_t stream)
{
    const float* x   = (const float*)d_in[0];
    const float* Wq  = (const float*)d_in[1];
    const float* bq  = (const float*)d_in[2];
    const float* Wk  = (const float*)d_in[3];
    const float* bk  = (const float*)d_in[4];
    const float* Wv  = (const float*)d_in[5];
    const float* bv  = (const float*)d_in[6];
    const float* Wo  = (const float*)d_in[7];
    const float* bo  = (const float*)d_in[8];
    const float* tha = (const float*)d_in[9];
    const float* thf = (const float*)d_in[10];
    const float* W1  = (const float*)d_in[11];
    const float* b1  = (const float*)d_in[12];
    const float* W2  = (const float*)d_in[13];
    const float* b2  = (const float*)d_in[14];
    const float* g1  = (const float*)d_in[15];
    const float* be1 = (const float*)d_in[16];
    const float* g2  = (const float*)d_in[17];
    const float* be2 = (const float*)d_in[18];

    // workspace: qb(2M) kb(2M) vb(2M) attn(4M)
    char* wsb = (char*)d_ws;
    unsigned short* qbp = (unsigned short*)(wsb);
    unsigned short* kbp = (unsigned short*)(wsb + (2u << 20));
    unsigned short* vbp = (unsigned short*)(wsb + (4u << 20));
    float* attn = (float*)(wsb + (6u << 20));

    qkv_kernel<<<512, 512, 0, stream>>>(x, Wq, bq, Wk, bk, Wv, bv, tha, qbp, kbp, vbp);
    attn_kernel<<<1024, 256, 0, stream>>>(qbp, kbp, vbp, attn);
    tail_kernel<<<512, 512, 0, stream>>>(attn, x, Wo, bo, g1, be1, thf,
                                         W1, b1, W2, b2, g2, be2, (float*)d_out);
}

// Round 5
// 158.605 us; speedup vs baseline: 1.5022x; 1.0430x over previous
//
#include <hip/hip_runtime.h>
#include <hip/hip_bf16.h>

#define B_ 8
#define T_ 2048
#define NROWS 16384

typedef __attribute__((ext_vector_type(4))) float f32x4;
typedef __attribute__((ext_vector_type(16))) float f32x16;
typedef __attribute__((ext_vector_type(8))) short short8;
typedef __fp16 half2_t __attribute__((ext_vector_type(2)));

__device__ __forceinline__ unsigned int pkrtz(float a, float b) {
    half2_t h = __builtin_amdgcn_cvt_pkrtz(a, b);
    return __builtin_bit_cast(unsigned int, h);
}
// pack two fp32 into one dword of bf16 (truncate): low short = a, high = b
__device__ __forceinline__ unsigned int pkbf(float a, float b) {
    return __builtin_amdgcn_perm(__float_as_uint(b), __float_as_uint(a), 0x07060302u);
}
__device__ __forceinline__ float dot2(unsigned int a, unsigned int b, float c) {
    return __builtin_amdgcn_fdot2(__builtin_bit_cast(half2_t, a),
                                  __builtin_bit_cast(half2_t, b), c, false);
}
__device__ __forceinline__ float fast_exp2(float x) {
#if __has_builtin(__builtin_amdgcn_exp2f)
    return __builtin_amdgcn_exp2f(x);
#else
    return exp2f(x);
#endif
}

// ---------------------------------------------------------------------------
// Kernel 1: QKV projection (dot2) + cos(.+theta) + bf16 pack to [B,H,T,DK].
// 64 rows/block, 2 rows x 12 cols per thread (halves LDS B-reads per output).
// Output through flat LDS tile -> linear b128 re-read -> coalesced uint4
// stores with wave-uniform buffer/head. q scaled by log2(e)/sqrt(8).
// ---------------------------------------------------------------------------
__global__ __launch_bounds__(512, 2) void qkv_kernel(
    const float* __restrict__ x,
    const float* __restrict__ Wq, const float* __restrict__ bq,
    const float* __restrict__ Wk, const float* __restrict__ bk,
    const float* __restrict__ Wv, const float* __restrict__ bv,
    const float* __restrict__ theta_attn,
    unsigned short* __restrict__ qb, unsigned short* __restrict__ kbuf,
    unsigned short* __restrict__ vbuf)
{
    __shared__ unsigned int xpk[32 * 66];     // fp16 pairs of x^T: [kpair][row0..63]
    __shared__ unsigned int wpk[32 * 196];    // fp16 pairs of W^T: [kpair][col0..191]
    __shared__ unsigned int outs[6144];       // bf16 out: [(c>>3)][row][4 dwords] linear
    const int tid = threadIdx.x;
    const int n0 = blockIdx.x * 64;

    #pragma unroll
    for (int t = 0; t < 2; t++) {             // 1024 float4 = 64x64 x
        int fi = tid + t * 512;
        float4 v = ((const float4*)(x + (size_t)n0 * 64))[fi];
        int r = fi >> 4, k0 = (fi & 15) * 4;
        xpk[(k0 >> 1) * 66 + r] = pkrtz(v.x, v.y);
        xpk[((k0 >> 1) + 1) * 66 + r] = pkrtz(v.z, v.w);
    }
    const float* Wm[3] = {Wq, Wk, Wv};
    #pragma unroll
    for (int t = 0; t < 6; t++) {             // 3072 float4 = 3 x (64x64)
        int fi = tid + t * 512;
        int m = fi >> 10, j = (fi >> 4) & 63, k0 = (fi & 15) * 4;
        float4 v = ((const float4*)Wm[m])[fi & 1023];
        wpk[(k0 >> 1) * 196 + m * 64 + j] = pkrtz(v.x, v.y);
        wpk[((k0 >> 1) + 1) * 196 + m * 64 + j] = pkrtz(v.z, v.w);
    }
    __syncthreads();

    const int r0 = (tid & 31) * 2;            // 2 rows
    const int c0 = (tid >> 5) * 12;           // x 12 cols
    float acc[2][12] = {};
    #pragma unroll 8
    for (int kp = 0; kp < 32; kp++) {
        uint2 a = *(const uint2*)&xpk[kp * 66 + r0];
        uint4 b0 = *(const uint4*)&wpk[kp * 196 + c0];
        uint4 b1 = *(const uint4*)&wpk[kp * 196 + c0 + 4];
        uint4 b2 = *(const uint4*)&wpk[kp * 196 + c0 + 8];
        unsigned int bb[12] = {b0.x, b0.y, b0.z, b0.w,
                               b1.x, b1.y, b1.z, b1.w,
                               b2.x, b2.y, b2.z, b2.w};
        #pragma unroll
        for (int j = 0; j < 12; j++) {
            acc[0][j] = dot2(a.x, bb[j], acc[0][j]);
            acc[1][j] = dot2(a.y, bb[j], acc[1][j]);
        }
    }

    {
        const float th = *theta_attn;
        const float QS = 0.51006980f;         // log2(e)/sqrt(8)
        const float* biasp[3] = {bq, bk, bv};
        float bcol[12];
        #pragma unroll
        for (int j = 0; j < 12; j++) {
            int c = c0 + j;
            bcol[j] = biasp[c >> 6][c & 63];
        }
        #pragma unroll
        for (int i = 0; i < 2; i++) {
            float vals[12];
            #pragma unroll
            for (int j = 0; j < 12; j++) {
                float v = __cosf(acc[i][j] + bcol[j] + th);
                vals[j] = ((c0 + j) >> 6) == 0 ? v * QS : v;
            }
            int row = r0 + i;
            #pragma unroll
            for (int t = 0; t < 6; t++) {
                int c = c0 + 2 * t;
                outs[(c >> 3) * 256 + row * 4 + ((c & 7) >> 1)] = pkbf(vals[2*t], vals[2*t+1]);
            }
        }
    }
    __syncthreads();

    unsigned short* outp3[3] = {qb, kbuf, vbuf};
    #pragma unroll
    for (int t = 0; t < 3; t++) {             // 1536 uint4 stores, linear LDS re-read
        int fi = tid + t * 512;
        int bh = fi >> 6, r2 = fi & 63;       // bh wave-uniform
        int m = bh >> 3, hI = bh & 7;
        uint4 v = *(const uint4*)&outs[4 * fi];
        int n = n0 + r2;
        unsigned short* dst = outp3[m] +
            ((size_t)((n >> 11) * 8 + hI) * 2048 + (n & 2047)) * 8;
        *(uint4*)dst = v;
    }
}

// ---------------------------------------------------------------------------
// Kernel 2: flash attention, S^T formulation, 32x32x16 bf16 MFMA.
// PV uses a k<->s permutation (bit2<->bit3 swizzle) applied to BOTH operands:
// each lane's own S^T C-regs form its PV B-frag (8 v_perm packs, NO shfl,
// NO cndmask), V^T read with two swizzled b64s. No-max softmax exact
// (|s| <= 8/sqrt(8)).
// ---------------------------------------------------------------------------
__global__ __launch_bounds__(256, 4) void attn_kernel(
    const unsigned short* __restrict__ qb,
    const unsigned short* __restrict__ kbuf,
    const unsigned short* __restrict__ vbuf,
    float* __restrict__ attn)
{
    __shared__ unsigned short Ks[1024 * 8];   // K rows bf16, half of T
    __shared__ unsigned short Vt[8 * 1032];   // V^T bf16, padded stride
    const int tid = threadIdx.x;
    const int head = blockIdx.x >> 4;         // b*8 + h
    const int qblk = blockIdx.x & 15;
    const size_t hoff = (size_t)head * T_ * 8;
    const int wave = tid >> 6, lane = tid & 63;
    const int col = lane & 31, h = lane >> 5;
    const int q0 = qblk * 128 + wave * 32;

    const short8 z8 = {0, 0, 0, 0, 0, 0, 0, 0};
    short8 bqf = z8;                          // Q B-frag: n=q (lanes 0-31), k=d
    if (h == 0) bqf = *(const short8*)(qb + hoff + (size_t)(q0 + col) * 8);

    f32x16 oacc = {0.f,0.f,0.f,0.f,0.f,0.f,0.f,0.f,0.f,0.f,0.f,0.f,0.f,0.f,0.f,0.f};
    const f32x16 z16 = {0.f,0.f,0.f,0.f,0.f,0.f,0.f,0.f,0.f,0.f,0.f,0.f,0.f,0.f,0.f,0.f};
    float lsum = 0.f;

    for (int half = 0; half < 2; half++) {
        __syncthreads();
        {
            const uint4* kg = (const uint4*)(kbuf + hoff + (size_t)half * 1024 * 8);
            const uint4* vg = (const uint4*)(vbuf + hoff + (size_t)half * 1024 * 8);
            uint4* kl = (uint4*)Ks;
            #pragma unroll
            for (int it = 0; it < 4; it++) {
                int s = tid + it * 256;
                kl[s] = kg[s];
                union { uint4 u; unsigned short us[8]; } cv;
                cv.u = vg[s];
                #pragma unroll
                for (int d = 0; d < 8; d++) Vt[d * 1032 + s] = cv.us[d];
            }
        }
        __syncthreads();

        for (int s0 = 0; s0 < 1024; s0 += 32) {
            short8 ak = z8;                   // K A-frag: m=key, k=d
            if (h == 0) ak = *(const short8*)&Ks[(s0 + col) * 8];
            f32x16 S = __builtin_amdgcn_mfma_f32_32x32x16_bf16(ak, bqf, z16, 0, 0, 0);
            float p[16];
            #pragma unroll
            for (int rr = 0; rr < 16; rr++) {
                p[rr] = fast_exp2(S[rr]);
                lsum += p[rr];
            }
            #pragma unroll
            for (int g = 0; g < 2; g++) {     // keys [s0+16g, s0+16g+16)
                const float* pp = p + g * 8;
                union { unsigned int u[4]; short8 s; } bp;
                bp.u[0] = pkbf(pp[0], pp[1]);
                bp.u[1] = pkbf(pp[2], pp[3]);
                bp.u[2] = pkbf(pp[4], pp[5]);
                bp.u[3] = pkbf(pp[6], pp[7]);
                short8 av = z8;               // V^T A-frag, pi-swizzled s
                if (col < 8) {
                    const unsigned short* vp = &Vt[col * 1032 + s0 + g * 16 + h * 4];
                    union { uint2 u2[2]; short8 s; } va;
                    va.u2[0] = *(const uint2*)(vp);      // s-local {0..3}+4h
                    va.u2[1] = *(const uint2*)(vp + 8);  // s-local {8..11}+4h
                    av = va.s;
                }
                oacc = __builtin_amdgcn_mfma_f32_32x32x16_bf16(av, bp.s, oacc, 0, 0, 0);
            }
        }
    }

    lsum += __shfl_xor(lsum, 32);             // this lane held half the s-range
    const float inv = 1.0f / lsum;
    const int bI = head >> 3, hI = head & 7;
    const int q = q0 + col;
    #pragma unroll
    for (int rr = 0; rr < 4; rr++) {          // O^T regs 0-3: d = 4h + rr
        int d = 4 * h + rr;
        attn[((size_t)bI * 2048 + q) * 64 + hI * 8 + d] = oacc[rr] * inv;
    }
}

// ---------------------------------------------------------------------------
// Kernel 3 (fused tail): y=attn@Wo^T+bo; x1=LN(x+y); qout=cos(x1)cos(thf);
// h=relu(qout@W1^T+b1); f=h@W2^T+b2; out=LN(x1+f).
// 32 rows/block, 512 blocks (2 blocks/CU). GEMM1/GEMM3 share one 2rx4c
// 256-thread mapping so x1 stays in registers; GEMM3 is 4-fp blocked with
// uint4 h-row reads; h stored row-major so its writes are b128.
// ---------------------------------------------------------------------------
__global__ __launch_bounds__(512, 4) void tail_kernel(
    const float* __restrict__ attn, const float* __restrict__ x,
    const float* __restrict__ Wo, const float* __restrict__ bo,
    const float* __restrict__ g1, const float* __restrict__ be1,
    const float* __restrict__ theta_ffn,
    const float* __restrict__ W1, const float* __restrict__ b1,
    const float* __restrict__ W2, const float* __restrict__ b2,
    const float* __restrict__ g2, const float* __restrict__ be2,
    float* __restrict__ outp)
{
    __shared__ unsigned int Wbuf[10496];  // Wo [32][68] | W1p at +2176 [32][260]; W2p at +0 [128][68]
    __shared__ unsigned int qpk[32 * 34]; // qout fp16 pairs [kpair][row]
    __shared__ unsigned int Upk[32 * 132];// At pairs [32][34]; then hrow [32][132]
    const int tid = threadIdx.x;
    const int lane = tid & 63;
    const int n0 = blockIdx.x * 32;
    unsigned int* const W1p = Wbuf + 2176;
    unsigned int* const W2p = Wbuf;       // overwrites Wo+part of W1p after they die
    unsigned int* const hrow = Upk;       // overwrites At pairs after GEMM1

    // shared 256-thread mapping for GEMM1/ep1/GEMM3/ep3
    const int rp = ((tid >> 6) & 3) * 4 + (lane & 3);   // 0..15 (waves 0-3)
    const int r0 = rp * 2;
    const int c0 = ((lane >> 2) & 15) * 4;

    // ---- early global issues ----
    float4 atv = ((const float4*)(attn + (size_t)n0 * 64))[tid];
    float4 wo0 = ((const float4*)Wo)[tid];
    float4 wo1 = ((const float4*)Wo)[tid + 512];
    float4 xv0 = *(const float4*)(x + (size_t)(n0 + r0) * 64 + c0);
    float4 xv1 = *(const float4*)(x + (size_t)(n0 + r0 + 1) * 64 + c0);
    float4 w1r[8];
    #pragma unroll
    for (int t = 0; t < 8; t++) w1r[t] = ((const float4*)W1)[tid + t * 512];

    // ---- stage At [32][34] + Wo [32][68] ----
    {
        int r = tid >> 4, k0 = (tid & 15) * 4;
        Upk[(k0 >> 1) * 34 + r] = pkrtz(atv.x, atv.y);
        Upk[((k0 >> 1) + 1) * 34 + r] = pkrtz(atv.z, atv.w);
        Wbuf[(k0 >> 1) * 68 + r] = pkrtz(wo0.x, wo0.y);
        Wbuf[((k0 >> 1) + 1) * 68 + r] = pkrtz(wo0.z, wo0.w);
        int fi = tid + 512;
        int r2 = fi >> 4, k2 = (fi & 15) * 4;
        Wbuf[(k2 >> 1) * 68 + r2] = pkrtz(wo1.x, wo1.y);
        Wbuf[((k2 >> 1) + 1) * 68 + r2] = pkrtz(wo1.z, wo1.w);
    }
    __syncthreads();

    // ---- W1 regs -> W1p (all 512 threads) ----
    #pragma unroll
    for (int t = 0; t < 8; t++) {
        int fi = tid + t * 512;               // 4096 float4 = 256f x 64k
        int f = fi >> 4, k0 = (fi & 15) * 4;
        W1p[(k0 >> 1) * 260 + f] = pkrtz(w1r[t].x, w1r[t].y);
        W1p[((k0 >> 1) + 1) * 260 + f] = pkrtz(w1r[t].z, w1r[t].w);
    }

    // ---- GEMM1 + ep1 (256 threads) ----
    float x1v[2][4];
    if (tid < 256) {
        float acc1[2][4] = {};
        #pragma unroll 8
        for (int kp = 0; kp < 32; kp++) {
            uint2 a = *(const uint2*)&Upk[kp * 34 + r0];
            uint4 b = *(const uint4*)&Wbuf[kp * 68 + c0];
            unsigned int bb[4] = {b.x, b.y, b.z, b.w};
            #pragma unroll
            for (int j = 0; j < 4; j++) {
                acc1[0][j] = dot2(a.x, bb[j], acc1[0][j]);
                acc1[1][j] = dot2(a.y, bb[j], acc1[1][j]);
            }
        }
        float4 bo4 = *(const float4*)&bo[c0];
        float4 g14 = *(const float4*)&g1[c0];
        float4 be14 = *(const float4*)&be1[c0];
        float gg[4] = {g14.x, g14.y, g14.z, g14.w};
        float eb[4] = {be14.x, be14.y, be14.z, be14.w};
        float bb4[4] = {bo4.x, bo4.y, bo4.z, bo4.w};
        float cth = __cosf(*theta_ffn);
        #pragma unroll
        for (int i = 0; i < 2; i++) {
            float4 xv = i ? xv1 : xv0;
            float vv[4] = {xv.x + acc1[i][0] + bb4[0], xv.y + acc1[i][1] + bb4[1],
                           xv.z + acc1[i][2] + bb4[2], xv.w + acc1[i][3] + bb4[3]};
            float s1 = vv[0] + vv[1] + vv[2] + vv[3];
            float s2 = vv[0]*vv[0] + vv[1]*vv[1] + vv[2]*vv[2] + vv[3]*vv[3];
            #pragma unroll
            for (int m = 4; m <= 32; m <<= 1) {
                s1 += __shfl_xor(s1, m);
                s2 += __shfl_xor(s2, m);
            }
            float mean = s1 * 0.015625f;
            float rstd = rsqrtf(s2 * 0.015625f - mean * mean + 1e-5f);
            float qv[4];
            #pragma unroll
            for (int j = 0; j < 4; j++) {
                x1v[i][j] = (vv[j] - mean) * rstd * gg[j] + eb[j];
                qv[j] = __cosf(x1v[i][j]) * cth;
            }
            qpk[((c0 >> 1) + 0) * 34 + r0 + i] = pkrtz(qv[0], qv[1]);
            qpk[((c0 >> 1) + 1) * 34 + r0 + i] = pkrtz(qv[2], qv[3]);
        }
    }
    __syncthreads();

    // ---- W2 prefetch (in flight across GEMM2) ----
    float4 w2r[8];
    #pragma unroll
    for (int t = 0; t < 8; t++) w2r[t] = ((const float4*)W2)[tid + t * 512];

    // ---- GEMM2: h = relu(qout @ W1^T + b1) -> hrow (row-major pairs) ----
    {
        const int r2 = (tid & 15) * 2;        // 2 rows
        const int f0 = (tid >> 4) * 8;        // x 8 f
        float acc2[2][8] = {};
        #pragma unroll 4
        for (int kp = 0; kp < 32; kp++) {
            uint2 a = *(const uint2*)&qpk[kp * 34 + r2];
            uint4 b0 = *(const uint4*)&W1p[kp * 260 + f0];
            uint4 b1q = *(const uint4*)&W1p[kp * 260 + f0 + 4];
            unsigned int bb[8] = {b0.x, b0.y, b0.z, b0.w, b1q.x, b1q.y, b1q.z, b1q.w};
            #pragma unroll
            for (int j = 0; j < 8; j++) {
                acc2[0][j] = dot2(a.x, bb[j], acc2[0][j]);
                acc2[1][j] = dot2(a.y, bb[j], acc2[1][j]);
            }
        }
        float4 c1a = *(const float4*)&b1[f0];
        float4 c1b = *(const float4*)&b1[f0 + 4];
        float bb[8] = {c1a.x, c1a.y, c1a.z, c1a.w, c1b.x, c1b.y, c1b.z, c1b.w};
        #pragma unroll
        for (int i = 0; i < 2; i++) {
            float hv[8];
            #pragma unroll
            for (int j = 0; j < 8; j++) hv[j] = fmaxf(acc2[i][j] + bb[j], 0.f);
            uint4 hq;
            hq.x = pkrtz(hv[0], hv[1]); hq.y = pkrtz(hv[2], hv[3]);
            hq.z = pkrtz(hv[4], hv[5]); hq.w = pkrtz(hv[6], hv[7]);
            *(uint4*)&hrow[(r2 + i) * 132 + (f0 >> 1)] = hq;
        }
    }
    __syncthreads();

    // ---- W2 regs -> W2p [128 fpair][68] (Wo/W1p dead) ----
    #pragma unroll
    for (int t = 0; t < 8; t++) {
        int fi = tid + t * 512;               // 4096 float4 = 64e x 64 fgroups
        int e = fi >> 6, k0 = (fi & 63) * 4;
        W2p[(k0 >> 1) * 68 + e] = pkrtz(w2r[t].x, w2r[t].y);
        W2p[((k0 >> 1) + 1) * 68 + e] = pkrtz(w2r[t].z, w2r[t].w);
    }
    __syncthreads();

    // ---- GEMM3 + ep3 (256 threads, 4-fp blocked) ----
    if (tid < 256) {
        float acc3[2][4] = {};
        #pragma unroll 4
        for (int fp0 = 0; fp0 < 128; fp0 += 4) {
            uint4 a0 = *(const uint4*)&hrow[(r0 + 0) * 132 + fp0];
            uint4 a1 = *(const uint4*)&hrow[(r0 + 1) * 132 + fp0];
            uint4 b0 = *(const uint4*)&W2p[(fp0 + 0) * 68 + c0];
            uint4 b1q = *(const uint4*)&W2p[(fp0 + 1) * 68 + c0];
            uint4 b2q = *(const uint4*)&W2p[(fp0 + 2) * 68 + c0];
            uint4 b3q = *(const uint4*)&W2p[(fp0 + 3) * 68 + c0];
            unsigned int aa[2][4] = {{a0.x, a0.y, a0.z, a0.w},
                                     {a1.x, a1.y, a1.z, a1.w}};
            unsigned int bbb[4][4] = {{b0.x, b0.y, b0.z, b0.w},
                                      {b1q.x, b1q.y, b1q.z, b1q.w},
                                      {b2q.x, b2q.y, b2q.z, b2q.w},
                                      {b3q.x, b3q.y, b3q.z, b3q.w}};
            #pragma unroll
            for (int i = 0; i < 2; i++)
                #pragma unroll
                for (int j = 0; j < 4; j++) {
                    float t0 = dot2(aa[i][0], bbb[0][j], acc3[i][j]);
                    t0 = dot2(aa[i][1], bbb[1][j], t0);
                    t0 = dot2(aa[i][2], bbb[2][j], t0);
                    acc3[i][j] = dot2(aa[i][3], bbb[3][j], t0);
                }
        }
        float4 b24 = *(const float4*)&b2[c0];
        float4 g24 = *(const float4*)&g2[c0];
        float4 be24 = *(const float4*)&be2[c0];
        #pragma unroll
        for (int i = 0; i < 2; i++) {
            float vv[4] = {x1v[i][0] + acc3[i][0] + b24.x,
                           x1v[i][1] + acc3[i][1] + b24.y,
                           x1v[i][2] + acc3[i][2] + b24.z,
                           x1v[i][3] + acc3[i][3] + b24.w};
            float s1 = vv[0] + vv[1] + vv[2] + vv[3];
            float s2 = vv[0]*vv[0] + vv[1]*vv[1] + vv[2]*vv[2] + vv[3]*vv[3];
            #pragma unroll
            for (int m = 4; m <= 32; m <<= 1) {
                s1 += __shfl_xor(s1, m);
                s2 += __shfl_xor(s2, m);
            }
            float mean = s1 * 0.015625f;
            float rstd = rsqrtf(s2 * 0.015625f - mean * mean + 1e-5f);
            float4 o;
            o.x = (vv[0] - mean) * rstd * g24.x + be24.x;
            o.y = (vv[1] - mean) * rstd * g24.y + be24.y;
            o.z = (vv[2] - mean) * rstd * g24.z + be24.z;
            o.w = (vv[3] - mean) * rstd * g24.w + be24.w;
            *(float4*)(outp + (size_t)(n0 + r0 + i) * 64 + c0) = o;
        }
    }
}

// ---------------------------------------------------------------------------
extern "C" void kernel_launch(void* const* d_in, const int* in_sizes, int n_in,
                              void* d_out, int out_size, void* d_ws, size_t ws_size,
                              hipStream_t stream)
{
    const float* x   = (const float*)d_in[0];
    const float* Wq  = (const float*)d_in[1];
    const float* bq  = (const float*)d_in[2];
    const float* Wk  = (const float*)d_in[3];
    const float* bk  = (const float*)d_in[4];
    const float* Wv  = (const float*)d_in[5];
    const float* bv  = (const float*)d_in[6];
    const float* Wo  = (const float*)d_in[7];
    const float* bo  = (const float*)d_in[8];
    const float* tha = (const float*)d_in[9];
    const float* thf = (const float*)d_in[10];
    const float* W1  = (const float*)d_in[11];
    const float* b1  = (const float*)d_in[12];
    const float* W2  = (const float*)d_in[13];
    const float* b2  = (const float*)d_in[14];
    const float* g1  = (const float*)d_in[15];
    const float* be1 = (const float*)d_in[16];
    const float* g2  = (const float*)d_in[17];
    const float* be2 = (const float*)d_in[18];

    // workspace: qb(2M) kb(2M) vb(2M) attn(4M)
    char* wsb = (char*)d_ws;
    unsigned short* qbp = (unsigned short*)(wsb);
    unsigned short* kbp = (unsigned short*)(wsb + (2u << 20));
    unsigned short* vbp = (unsigned short*)(wsb + (4u << 20));
    float* attn = (float*)(wsb + (6u << 20));

    qkv_kernel<<<256, 512, 0, stream>>>(x, Wq, bq, Wk, bk, Wv, bv, tha, qbp, kbp, vbp);
    attn_kernel<<<1024, 256, 0, stream>>>(qbp, kbp, vbp, attn);
    tail_kernel<<<512, 512, 0, stream>>>(attn, x, Wo, bo, g1, be1, thf,
                                         W1, b1, W2, b2, g2, be2, (float*)d_out);
}